// Round 6
// baseline (191.992 us; speedup 1.0000x reference)
//
#include <hip/hip_runtime.h>
#include <hip/hip_fp16.h>
#include <math.h>

#define BB 2
#define CC 64
#define HH 256
#define WW 256
#define KK 9
#define NOFF 10          // offset channels needed (0..8 sampled, 9 completes GN group 4)
#define HW (HH*WW)

typedef __attribute__((ext_vector_type(8))) short s16x8;   // 8 fp16 = 4 VGPRs (MFMA A/B frag)
typedef __attribute__((ext_vector_type(4))) float f32x4;   // MFMA C/D frag

// lerp two packed-fp16 pairs: d = a + fy*(b-a)   (2 VALU: v_pk_sub + v_pk_fma)
__device__ __forceinline__ unsigned lerp2h(unsigned a, unsigned b, __half2 fy2) {
    __half2 ah = *(__half2*)&a, bh = *(__half2*)&b;
    __half2 d = __hfma2(fy2, __hsub2(bh, ah), ah);
    return *(unsigned*)&d;
}

// ---------------- transpose x: NCHW fp32 -> NHWC fp16 ; blocks >= 2048 pack weights ----------------
__global__ __launch_bounds__(256) void transpose_x_kernel(const float* __restrict__ x,
                                                          unsigned short* __restrict__ xTh,
                                                          const float* __restrict__ w_off,
                                                          const float* __restrict__ w_dsc,
                                                          unsigned short* __restrict__ woffB,
                                                          unsigned short* __restrict__ wdscB) {
    if (blockIdx.x >= 2048) {            // ---- weight packing (144 blocks) ----
        int idx = (blockIdx.x - 2048) * 256 + threadIdx.x;
        if (idx < 18 * 64 * 8) {
            int kb = idx >> 9;
            int L  = (idx >> 3) & 63;
            int j  = idx & 7;
            int n = L & 15, quad = L >> 4;
            int kk = kb * 32 + quad * 8 + j;
            int tap = kk >> 6, ci = kk & 63;
            float v = (n < NOFF) ? w_off[(n * 64 + ci) * 9 + tap] : 0.f;
            __half hv = __float2half(v);
            woffB[idx] = *(unsigned short*)&hv;
        }
        if (idx < 4 * 18 * 64 * 8) {
            int nt = idx / 9216;
            int r  = idx - nt * 9216;
            int kb = r >> 9;
            int L  = (r >> 3) & 63;
            int j  = r & 7;
            int n = L & 15, quad = L >> 4;
            int co = nt * 16 + n;
            int kk = kb * 32 + quad * 8 + j;
            int k = kk >> 6, ci = kk & 63;
            __half hv = __float2half(w_dsc[(co * 64 + ci) * 9 + k]);
            wdscB[idx] = *(unsigned short*)&hv;
        }
        return;
    }
    __shared__ float tile[64 * 65];
    int wt = blockIdx.x & 3;
    int h  = (blockIdx.x >> 2) & 255;
    int b  = blockIdx.x >> 10;
    int w0 = wt * 64;
    int t  = threadIdx.x;
    {
        int wl = t & 63, crow = t >> 6;
        for (int it = 0; it < 16; ++it) {
            int c = crow + it * 4;
            tile[wl * 65 + c] = x[(((b * CC + c) * HH + h) * WW) + w0 + wl];  // coalesced over w
        }
    }
    __syncthreads();
    {
        int c2 = t & 31, wrow = t >> 5;
        unsigned* dst = (unsigned*)xTh;
        for (int it = 0; it < 8; ++it) {
            int wl = wrow + it * 8;
            __half2 p = __floats2half2_rn(tile[wl * 65 + c2 * 2], tile[wl * 65 + c2 * 2 + 1]);
            dst[(((b * HH + h) * WW) + w0 + wl) * 32 + c2] = *(unsigned*)&p; // coalesced over c
        }
    }
}

// ---------------- offset conv 3x3 via MFMA, LDS-staged halo strip ----------------
#define CPITCH 72   // halves per pixel in conv LDS (16B-aligned, 2-way-free bank phase)
__global__ __launch_bounds__(256, 4) void conv_off_mfma(const unsigned short* __restrict__ xTh,
                                                        const unsigned short* __restrict__ woffB,
                                                        const float* __restrict__ b_off,
                                                        float* __restrict__ off_raw,
                                                        float* __restrict__ partials_off) {
    __shared__ unsigned short sx[3 * 66 * CPITCH];   // 28,512 B
    __shared__ float rs[4][16], rs2[4][16];
    int t = threadIdx.x;
    int L = t & 63, v = t >> 6;
    int b  = blockIdx.x >> 10;
    int h  = (blockIdx.x >> 2) & 255;
    int w0 = (blockIdx.x & 3) << 6;
    int col = L & 15, quad = L >> 4;

    // stage rows h-1..h+1, cols w0-1..w0+64, 64 ch fp16, zero-padded OOB
#pragma unroll
    for (int it = 0; it < 7; ++it) {
        int linear = it * 256 + t;
        if (linear < 1584) {                     // 3*66*8 chunk-items
            int dy  = linear / 528;
            int rem = linear - dy * 528;
            int px  = rem >> 3, cg = rem & 7;
            int y  = h - 1 + dy;
            int xc = w0 - 1 + px;
            uint4 d = make_uint4(0, 0, 0, 0);
            if ((unsigned)y < 256u && (unsigned)xc < 256u)
                d = *(const uint4*)(xTh + ((size_t)(((b << 8) + y) << 8) + xc) * 64 + cg * 8);
            *(uint4*)&sx[(dy * 66 + px) * CPITCH + cg * 8] = d;
        }
    }

    s16x8 breg[18];
#pragma unroll
    for (int kb = 0; kb < 18; ++kb)
        breg[kb] = *(const s16x8*)(woffB + (kb * 64 + L) * 8);
    __syncthreads();

    f32x4 acc = {0.f, 0.f, 0.f, 0.f};
#pragma unroll
    for (int kb = 0; kb < 18; ++kb) {
        int tap = kb >> 1;
        int dy = tap / 3, dxl = tap % 3;         // stage col 0 == w0-1
        int pxl = v * 16 + col + dxl;
        int ci0 = ((kb & 1) << 5) + quad * 8;
        s16x8 a = *(const s16x8*)&sx[(dy * 66 + pxl) * CPITCH + ci0];
        acc = __builtin_amdgcn_mfma_f32_16x16x32_f16(a, breg[kb], acc, 0, 0, 0);
    }
    int oc = col;                         // D col
    float bo = b_off[oc];
    float s = 0.f, s2 = 0.f;
#pragma unroll
    for (int r = 0; r < 4; ++r) {
        float val = acc[r] + bo;
        if (oc < NOFF) {
            int w = w0 + v * 16 + quad * 4 + r;  // D row
            off_raw[((b * NOFF + oc) << 16) + (h << 8) + w] = val;
        }
        s += val; s2 += val * val;
    }
    s  += __shfl_xor(s, 16, 64);  s  += __shfl_xor(s, 32, 64);
    s2 += __shfl_xor(s2, 16, 64); s2 += __shfl_xor(s2, 32, 64);
    if (quad == 0) { rs[v][oc] = s; rs2[v][oc] = s2; }
    __syncthreads();
    if (t < NOFF) {   // non-atomic per-block partials: [block][10][2]
        float a_ = rs[0][t] + rs[1][t] + rs[2][t] + rs[3][t];
        float a2 = rs2[0][t] + rs2[1][t] + rs2[2][t] + rs2[3][t];
        partials_off[(size_t)blockIdx.x * 20 + t * 2]     = a_;
        partials_off[(size_t)blockIdx.x * 20 + t * 2 + 1] = a2;
    }
}

// ---------------- reduce offset GN partials -> mean/rstd per (b, group-of-2ch) ----------------
__global__ __launch_bounds__(256) void reduce_off_kernel(const float* __restrict__ partials,
                                                         float* __restrict__ stats) {
    int bg = blockIdx.x;          // b*5+g
    int b = bg / 5, g = bg - b * 5;
    int t = threadIdx.x;
    float s = 0.f, s2 = 0.f;
    for (int i = t; i < 1024; i += 256) {
        const float* p = partials + ((size_t)(b * 1024 + i)) * 20 + g * 4;
        s  += p[0] + p[2];
        s2 += p[1] + p[3];
    }
    __shared__ float rs[256], rs2[256];
    rs[t] = s; rs2[t] = s2;
    __syncthreads();
    for (int o = 128; o > 0; o >>= 1) {
        if (t < o) { rs[t] += rs[t + o]; rs2[t] += rs2[t + o]; }
        __syncthreads();
    }
    if (t == 0) {
        float mean = rs[0] * (1.f / 131072.f);
        float var  = rs2[0] * (1.f / 131072.f) - mean * mean;
        stats[bg * 2]     = mean;
        stats[bg * 2 + 1] = rsqrtf(var + 1e-5f);
    }
}

// ---------------- reduce output GN partials -> mean/rstd per (b, group-of-4ch) ----------------
__global__ __launch_bounds__(256) void reduce_out_kernel(const float* __restrict__ partials,
                                                         float* __restrict__ stats) {
    int bg = blockIdx.x;          // b*16+g
    int b = bg >> 4, g = bg & 15;
    int t = threadIdx.x;
    float s = 0.f, s2 = 0.f;
    for (int i = t; i < 1024; i += 256) {
        const float* p = partials + ((size_t)(b * 1024 + i)) * 32 + g * 2;
        s  += p[0];
        s2 += p[1];
    }
    __shared__ float rs[256], rs2[256];
    rs[t] = s; rs2[t] = s2;
    __syncthreads();
    for (int o = 128; o > 0; o >>= 1) {
        if (t < o) { rs[t] += rs[t + o]; rs2[t] += rs2[t + o]; }
        __syncthreads();
    }
    if (t == 0) {
        float mean = rs[0] * (1.f / 262144.f);
        float var  = rs2[0] * (1.f / 262144.f) - mean * mean;
        stats[bg * 2]     = mean;
        stats[bg * 2 + 1] = rsqrtf(var + 1e-5f);
    }
}

// ---------------- fused main: GN+tanh+cumsum -> fp16 packed lerp -> MFMA -> GN partials ----------------
// LDS 24,448 B -> 6 blocks/CU (24 waves/CU); 4 rounds of 16 px
__global__ __launch_bounds__(256, 6) void main_mfma(const unsigned short* __restrict__ xTh,
                                                    const float* __restrict__ off_raw,
                                                    const float* __restrict__ stats_off,
                                                    const float* __restrict__ gno_w,
                                                    const float* __restrict__ gno_b,
                                                    const unsigned short* __restrict__ wdscB,
                                                    const float* __restrict__ b_dsc,
                                                    unsigned short* __restrict__ tmph,
                                                    float* __restrict__ partials_out) {
    __shared__ unsigned short aT[16 * 584];   // 18,688 B: 16 px rows, pitch 584 halves
    __shared__ int            offA0[576];     //  2,304 B: 64 px * 9 k, y0-row element offsets
    __shared__ unsigned short fyH[576];       //  1,152 B: fy as fp16
    __shared__ float          tkL[576];       //  2,304 B: tanh values [w][k]

    int t = threadIdx.x;
    int L = t & 63, nt = t >> 6;
    int b  = blockIdx.x >> 10;
    int h  = (blockIdx.x >> 2) & 255;
    int w0 = (blockIdx.x & 3) << 6;

    // Phase A1: 576 GN+tanh evals spread over all 256 threads (k-major for coalescing)
    for (int i = t; i < 576; i += 256) {
        int k = i >> 6, w = i & 63;
        float vv = off_raw[((b * NOFF + k) << 16) + (h << 8) + w0 + w];
        int g = k >> 1;
        float mean = stats_off[(b * 5 + g) * 2];
        float rstd = stats_off[(b * 5 + g) * 2 + 1];
        tkL[w * 9 + k] = tanhf((vv - mean) * rstd * gno_w[k] + gno_b[k]);
    }

    s16x8 wreg[18];
#pragma unroll
    for (int kb = 0; kb < 18; ++kb)
        wreg[kb] = *(const s16x8*)(wdscB + ((nt * 18 + kb) * 64 + L) * 8);

    __syncthreads();

    // Phase A2: 64 threads, one pixel each: outward cumsum -> sample coords
    if (t < 64) {
        int w = w0 + t;
        float tk[9];
#pragma unroll
        for (int k = 0; k < 9; ++k) tk[k] = tkL[t * 9 + k];
        float yc[9];
        float c = 0.f;
#pragma unroll
        for (int k = 3; k >= 0; --k) { c += tk[k]; yc[k] = c; }
        yc[4] = 0.f;
        c = 0.f;
#pragma unroll
        for (int k = 5; k < 9; ++k) { c += tk[k]; yc[k] = c; }
#pragma unroll
        for (int k = 0; k < 9; ++k) {
            float y = fminf(fmaxf((float)h + yc[k], 0.f), 255.f);
            float y0f = floorf(y);
            int y0 = (int)y0f;
            int xc = min(max(w + k - 4, 0), 255);
            offA0[t * 9 + k] = ((b * 256 + y0) * 256 + xc) * 64;
            __half fh = __float2half(y - y0f);
            fyH[t * 9 + k] = *(unsigned short*)&fh;
        }
    }

    int col = L & 15, quad = L >> 4;
    int co = nt * 16 + col;
    float bias = b_dsc[co];
    float ss = 0.f, ss2 = 0.f;

    for (int round = 0; round < 4; ++round) {
        __syncthreads();   // offA ready (round 0) / aT free (rounds 1-3)
        // stage 16 px: 16*9*8 = 1152 chunk-items
        for (int idx = t; idx < 1152; idx += 256) {
            int cg  = idx & 7;
            int r2  = idx >> 3;            // 0..143
            int pxl = r2 / 9;
            int k   = r2 - pxl * 9;
            int pi  = (round * 16 + pxl) * 9 + k;
            int o0 = offA0[pi] + cg * 8;
            unsigned short fb = fyH[pi];
            int o1 = fb ? o0 + 16384 : o0;      // +1 row (256*64) iff fy != 0
            __half fh = *(__half*)&fb;
            __half2 fy2 = __half2half2(fh);
            uint4 u0 = *(const uint4*)(xTh + o0);
            uint4 u1 = *(const uint4*)(xTh + o1);
            uint4 d;
            d.x = lerp2h(u0.x, u1.x, fy2);
            d.y = lerp2h(u0.y, u1.y, fy2);
            d.z = lerp2h(u0.z, u1.z, fy2);
            d.w = lerp2h(u0.w, u1.w, fy2);
            int c2 = (cg + k) & 7;
            *(uint4*)&aT[pxl * 584 + k * 64 + c2 * 8] = d;
        }
        __syncthreads();

        f32x4 acc = {0.f, 0.f, 0.f, 0.f};
#pragma unroll
        for (int kb = 0; kb < 18; ++kb) {
            int k  = kb >> 1;
            int cch = ((kb & 1) << 2) + quad;
            int c2 = (cch + k) & 7;
            s16x8 a = *(const s16x8*)&aT[col * 584 + k * 64 + c2 * 8];
            acc = __builtin_amdgcn_mfma_f32_16x16x32_f16(a, wreg[kb], acc, 0, 0, 0);
        }
        int wbase = w0 + round * 16 + quad * 4;
        size_t obase = ((size_t)((b << 16) + (h << 8) + wbase)) * 64 + co;
#pragma unroll
        for (int r = 0; r < 4; ++r) {
            float val = acc[r] + bias;
            ss += val; ss2 += val * val;
            __half hv = __float2half(val);
            tmph[obase + (size_t)r * 64] = *(unsigned short*)&hv;
        }
    }
    // per-block GN partials: sum over 64 px (quads) then over the 4 channels of each group
    ss  += __shfl_xor(ss, 16, 64);  ss  += __shfl_xor(ss, 32, 64);
    ss2 += __shfl_xor(ss2, 16, 64); ss2 += __shfl_xor(ss2, 32, 64);
    float sg = ss, sg2 = ss2;
    sg  += __shfl_xor(sg, 1, 64);  sg  += __shfl_xor(sg, 2, 64);
    sg2 += __shfl_xor(sg2, 1, 64); sg2 += __shfl_xor(sg2, 2, 64);
    if (quad == 0 && (col & 3) == 0) {
        int gi = nt * 4 + (col >> 2);      // 0..15
        partials_out[(size_t)blockIdx.x * 32 + gi * 2]     = sg;
        partials_out[(size_t)blockIdx.x * 32 + gi * 2 + 1] = sg2;
    }
}

// ---------------- final: NHWC fp16 tmp -> GN -> ReLU -> NCHW fp32 out ----------------
__global__ __launch_bounds__(256) void apply_final_kernel(const unsigned short* __restrict__ tmph,
                                                          const float* __restrict__ stats_out,
                                                          const float* __restrict__ gn_w,
                                                          const float* __restrict__ gn_b,
                                                          float* __restrict__ out) {
    __shared__ float tile[64 * 65];
    int wt = blockIdx.x & 3;
    int h  = (blockIdx.x >> 2) & 255;
    int b  = blockIdx.x >> 10;
    int w0 = wt * 64;
    int t  = threadIdx.x;
    {
        int c2 = t & 31, wrow = t >> 5;
        int co0 = c2 * 2;
        int g = co0 >> 2;
        float mean = stats_out[(b * 16 + g) * 2];
        float rstd = stats_out[(b * 16 + g) * 2 + 1];
        float sc0 = rstd * gn_w[co0],     sh0 = gn_b[co0]     - mean * sc0;
        float sc1 = rstd * gn_w[co0 + 1], sh1 = gn_b[co0 + 1] - mean * sc1;
        const unsigned* src = (const unsigned*)tmph;
        for (int it = 0; it < 8; ++it) {
            int wl = wrow + it * 8;
            unsigned u = src[(((b * HH + h) * WW) + w0 + wl) * 32 + c2];  // coalesced over c
            float2 f = __half22float2(*(__half2*)&u);
            tile[co0 * 65 + wl]       = fmaxf(fmaf(f.x, sc0, sh0), 0.f);
            tile[(co0 + 1) * 65 + wl] = fmaxf(fmaf(f.y, sc1, sh1), 0.f);
        }
    }
    __syncthreads();
    {
        int wl = t & 63, crow = t >> 6;
        for (int it = 0; it < 16; ++it) {
            int co = crow + it * 4;
            out[((size_t)(b * CC + co) * HH + h) * WW + w0 + wl] = tile[co * 65 + wl];
        }
    }
}

extern "C" void kernel_launch(void* const* d_in, const int* in_sizes, int n_in,
                              void* d_out, int out_size, void* d_ws, size_t ws_size,
                              hipStream_t stream) {
    const float* x     = (const float*)d_in[0];
    const float* w_off = (const float*)d_in[1];
    const float* b_off = (const float*)d_in[2];
    const float* gno_w = (const float*)d_in[3];
    const float* gno_b = (const float*)d_in[4];
    const float* w_dsc = (const float*)d_in[5];
    const float* b_dsc = (const float*)d_in[6];
    const float* gn_w  = (const float*)d_in[7];
    const float* gn_b  = (const float*)d_in[8];
    float* out = (float*)d_out;

    char* ws = (char*)d_ws;
    unsigned short* xTh   = (unsigned short*)(ws);                 // 16,777,216 B
    unsigned short* tmph  = (unsigned short*)(ws + 16777216);      // 16,777,216 B
    float* off_raw        = (float*)(ws + 33554432);               //  5,242,880 B
    unsigned short* wdscB = (unsigned short*)(ws + 38797312);      //     73,728 B
    unsigned short* woffB = (unsigned short*)(ws + 38871040);      //     18,432 B
    float* stats_off      = (float*)(ws + 38889472);               //         80 B (pad to 256)
    float* stats_out      = (float*)(ws + 38889728);               //        256 B (pad to 768)
    float* partials_off   = (float*)(ws + 38890496);               //    163,840 B
    float* partials_out   = (float*)(ws + 39054336);               //    262,144 B

    hipLaunchKernelGGL(transpose_x_kernel, dim3(2192), dim3(256), 0, stream,
                       x, xTh, w_off, w_dsc, woffB, wdscB);
    hipLaunchKernelGGL(conv_off_mfma, dim3(2048), dim3(256), 0, stream,
                       xTh, woffB, b_off, off_raw, partials_off);
    hipLaunchKernelGGL(reduce_off_kernel, dim3(10), dim3(256), 0, stream,
                       partials_off, stats_off);
    hipLaunchKernelGGL(main_mfma, dim3(2048), dim3(256), 0, stream,
                       xTh, off_raw, stats_off, gno_w, gno_b, wdscB, b_dsc,
                       tmph, partials_out);
    hipLaunchKernelGGL(reduce_out_kernel, dim3(32), dim3(256), 0, stream,
                       partials_out, stats_out);
    hipLaunchKernelGGL(apply_final_kernel, dim3(2048), dim3(256), 0, stream,
                       tmph, stats_out, gn_w, gn_b, out);
}

// Round 7
// 156.690 us; speedup vs baseline: 1.2253x; 1.2253x over previous
//
#include <hip/hip_runtime.h>
#include <hip/hip_fp16.h>
#include <math.h>

#define BB 2
#define CC 64
#define HH 256
#define WW 256
#define KK 9
#define NOFF 10          // offset channels needed (0..8 sampled, 9 completes GN group 4)
#define HW (HH*WW)

typedef __attribute__((ext_vector_type(8))) short s16x8;   // 8 fp16 = 4 VGPRs (MFMA A/B frag)
typedef __attribute__((ext_vector_type(4))) float f32x4;   // MFMA C/D frag

// lerp two packed-fp16 pairs: d = a + fy*(b-a)   (2 VALU: v_pk_sub + v_pk_fma)
__device__ __forceinline__ unsigned lerp2h(unsigned a, unsigned b, __half2 fy2) {
    __half2 ah = *(__half2*)&a, bh = *(__half2*)&b;
    __half2 d = __hfma2(fy2, __hsub2(bh, ah), ah);
    return *(unsigned*)&d;
}

// XCD band swizzle: assume xcd = blockIdx % 8 (round-robin dispatch). Give each
// XCD a contiguous 64-row h-band so its resident blocks share a small rolling
// row window in its private 4 MB L2. Decode: W = xcd*256 + i -> (b, h, wt).
__device__ __forceinline__ void swizzle_bhw(int g, int& b, int& h, int& wt) {
    int W = ((g & 7) << 8) | (g >> 3);
    b  = W >> 10;
    int rem = W & 1023;
    h  = rem >> 2;
    wt = rem & 3;
}

// ---------------- transpose x: NCHW fp32 -> NHWC fp16 ; blocks >= 2048 pack weights ----------------
__global__ __launch_bounds__(256) void transpose_x_kernel(const float* __restrict__ x,
                                                          unsigned short* __restrict__ xTh,
                                                          const float* __restrict__ w_off,
                                                          const float* __restrict__ w_dsc,
                                                          unsigned short* __restrict__ woffB,
                                                          unsigned short* __restrict__ wdscB) {
    if (blockIdx.x >= 2048) {            // ---- weight packing (144 blocks) ----
        int idx = (blockIdx.x - 2048) * 256 + threadIdx.x;
        if (idx < 18 * 64 * 8) {
            int kb = idx >> 9;
            int L  = (idx >> 3) & 63;
            int j  = idx & 7;
            int n = L & 15, quad = L >> 4;
            int kk = kb * 32 + quad * 8 + j;
            int tap = kk >> 6, ci = kk & 63;
            float v = (n < NOFF) ? w_off[(n * 64 + ci) * 9 + tap] : 0.f;
            __half hv = __float2half(v);
            woffB[idx] = *(unsigned short*)&hv;
        }
        if (idx < 4 * 18 * 64 * 8) {
            int nt = idx / 9216;
            int r  = idx - nt * 9216;
            int kb = r >> 9;
            int L  = (r >> 3) & 63;
            int j  = r & 7;
            int n = L & 15, quad = L >> 4;
            int co = nt * 16 + n;
            int kk = kb * 32 + quad * 8 + j;
            int k = kk >> 6, ci = kk & 63;
            __half hv = __float2half(w_dsc[(co * 64 + ci) * 9 + k]);
            wdscB[idx] = *(unsigned short*)&hv;
        }
        return;
    }
    __shared__ float tile[64 * 65];
    int wt = blockIdx.x & 3;
    int h  = (blockIdx.x >> 2) & 255;
    int b  = blockIdx.x >> 10;
    int w0 = wt * 64;
    int t  = threadIdx.x;
    {
        int wl = t & 63, crow = t >> 6;
        for (int it = 0; it < 16; ++it) {
            int c = crow + it * 4;
            tile[wl * 65 + c] = x[(((b * CC + c) * HH + h) * WW) + w0 + wl];  // coalesced over w
        }
    }
    __syncthreads();
    {
        int c2 = t & 31, wrow = t >> 5;
        unsigned* dst = (unsigned*)xTh;
        for (int it = 0; it < 8; ++it) {
            int wl = wrow + it * 8;
            __half2 p = __floats2half2_rn(tile[wl * 65 + c2 * 2], tile[wl * 65 + c2 * 2 + 1]);
            dst[(((b * HH + h) * WW) + w0 + wl) * 32 + c2] = *(unsigned*)&p; // coalesced over c
        }
    }
}

// ---------------- offset conv 3x3 via MFMA, LDS-staged halo strip ----------------
#define CPITCH 72   // halves per pixel in conv LDS (16B-aligned, 2-way-free bank phase)
__global__ __launch_bounds__(256, 4) void conv_off_mfma(const unsigned short* __restrict__ xTh,
                                                        const unsigned short* __restrict__ woffB,
                                                        const float* __restrict__ b_off,
                                                        unsigned short* __restrict__ off_raw,
                                                        float* __restrict__ partials_off) {
    __shared__ unsigned short sx[3 * 66 * CPITCH];   // 28,512 B
    __shared__ float rs[4][16], rs2[4][16];
    int t = threadIdx.x;
    int L = t & 63, v = t >> 6;
    int b, h, wt;
    swizzle_bhw(blockIdx.x, b, h, wt);
    int w0 = wt << 6;
    int col = L & 15, quad = L >> 4;

    // stage rows h-1..h+1, cols w0-1..w0+64, 64 ch fp16, zero-padded OOB
#pragma unroll
    for (int it = 0; it < 7; ++it) {
        int linear = it * 256 + t;
        if (linear < 1584) {                     // 3*66*8 chunk-items
            int dy  = linear / 528;
            int rem = linear - dy * 528;
            int px  = rem >> 3, cg = rem & 7;
            int y  = h - 1 + dy;
            int xc = w0 - 1 + px;
            uint4 d = make_uint4(0, 0, 0, 0);
            if ((unsigned)y < 256u && (unsigned)xc < 256u)
                d = *(const uint4*)(xTh + ((size_t)(((b << 8) + y) << 8) + xc) * 64 + cg * 8);
            *(uint4*)&sx[(dy * 66 + px) * CPITCH + cg * 8] = d;
        }
    }

    s16x8 breg[18];
#pragma unroll
    for (int kb = 0; kb < 18; ++kb)
        breg[kb] = *(const s16x8*)(woffB + (kb * 64 + L) * 8);
    __syncthreads();

    f32x4 acc = {0.f, 0.f, 0.f, 0.f};
#pragma unroll
    for (int kb = 0; kb < 18; ++kb) {
        int tap = kb >> 1;
        int dy = tap / 3, dxl = tap % 3;         // stage col 0 == w0-1
        int pxl = v * 16 + col + dxl;
        int ci0 = ((kb & 1) << 5) + quad * 8;
        s16x8 a = *(const s16x8*)&sx[(dy * 66 + pxl) * CPITCH + ci0];
        acc = __builtin_amdgcn_mfma_f32_16x16x32_f16(a, breg[kb], acc, 0, 0, 0);
    }
    int oc = col;                         // D col
    float bo = b_off[oc];
    float s = 0.f, s2 = 0.f;
#pragma unroll
    for (int r = 0; r < 4; ++r) {
        float val = acc[r] + bo;
        if (oc < NOFF) {
            int w = w0 + v * 16 + quad * 4 + r;  // D row
            __half hv = __float2half(val);
            off_raw[((b * NOFF + oc) << 16) + (h << 8) + w] = *(unsigned short*)&hv;
        }
        s += val; s2 += val * val;
    }
    s  += __shfl_xor(s, 16, 64);  s  += __shfl_xor(s, 32, 64);
    s2 += __shfl_xor(s2, 16, 64); s2 += __shfl_xor(s2, 32, 64);
    if (quad == 0) { rs[v][oc] = s; rs2[v][oc] = s2; }
    __syncthreads();
    if (t < NOFF) {   // non-atomic per-block partials: [block][10][2]
        float a_ = rs[0][t] + rs[1][t] + rs[2][t] + rs[3][t];
        float a2 = rs2[0][t] + rs2[1][t] + rs2[2][t] + rs2[3][t];
        partials_off[(size_t)blockIdx.x * 20 + t * 2]     = a_;
        partials_off[(size_t)blockIdx.x * 20 + t * 2 + 1] = a2;
    }
}

// ---------------- reduce offset GN partials -> mean/rstd per (b, group-of-2ch) ----------------
__global__ __launch_bounds__(256) void reduce_off_kernel(const float* __restrict__ partials,
                                                         float* __restrict__ stats) {
    int bg = blockIdx.x;          // b*5+g
    int t = threadIdx.x;
    float s = 0.f, s2 = 0.f;
    // partials are block-indexed with the swizzle; sum is order-invariant, but b
    // lives in the swizzled W: block g covers b = ((g&7)<<8 | g>>3) >> 10.
    int b = bg / 5, gg = bg - b * 5;
    for (int i = t; i < 2048; i += 256) {
        int blk_b = (((i & 7) << 8) | (i >> 3)) >> 10;
        if (blk_b == b) {
            const float* p = partials + (size_t)i * 20 + gg * 4;
            s  += p[0] + p[2];
            s2 += p[1] + p[3];
        }
    }
    __shared__ float rs[256], rs2[256];
    rs[t] = s; rs2[t] = s2;
    __syncthreads();
    for (int o = 128; o > 0; o >>= 1) {
        if (t < o) { rs[t] += rs[t + o]; rs2[t] += rs2[t + o]; }
        __syncthreads();
    }
    if (t == 0) {
        float mean = rs[0] * (1.f / 131072.f);
        float var  = rs2[0] * (1.f / 131072.f) - mean * mean;
        stats[bg * 2]     = mean;
        stats[bg * 2 + 1] = rsqrtf(var + 1e-5f);
    }
}

// ---------------- reduce output GN partials -> mean/rstd per (b, group-of-4ch) ----------------
__global__ __launch_bounds__(256) void reduce_out_kernel(const float* __restrict__ partials,
                                                         float* __restrict__ stats) {
    int bg = blockIdx.x;          // b*16+g
    int b = bg >> 4, g = bg & 15;
    int t = threadIdx.x;
    float s = 0.f, s2 = 0.f;
    for (int i = t; i < 2048; i += 256) {
        int blk_b = (((i & 7) << 8) | (i >> 3)) >> 10;
        if (blk_b == b) {
            const float* p = partials + (size_t)i * 32 + g * 2;
            s  += p[0];
            s2 += p[1];
        }
    }
    __shared__ float rs[256], rs2[256];
    rs[t] = s; rs2[t] = s2;
    __syncthreads();
    for (int o = 128; o > 0; o >>= 1) {
        if (t < o) { rs[t] += rs[t + o]; rs2[t] += rs2[t + o]; }
        __syncthreads();
    }
    if (t == 0) {
        float mean = rs[0] * (1.f / 262144.f);
        float var  = rs2[0] * (1.f / 262144.f) - mean * mean;
        stats[bg * 2]     = mean;
        stats[bg * 2 + 1] = rsqrtf(var + 1e-5f);
    }
}

// ---------------- fused main: GN+tanh+cumsum -> fp16 packed lerp -> MFMA -> GN partials ----------------
// LDS 39,680 B -> 4 blocks/CU; 2 rounds of 32 px (R5 structure); XCD band swizzle
__global__ __launch_bounds__(256, 4) void main_mfma(const unsigned short* __restrict__ xTh,
                                                    const unsigned short* __restrict__ off_raw,
                                                    const float* __restrict__ stats_off,
                                                    const float* __restrict__ gno_w,
                                                    const float* __restrict__ gno_b,
                                                    const unsigned short* __restrict__ wdscB,
                                                    const float* __restrict__ b_dsc,
                                                    unsigned short* __restrict__ tmph,
                                                    float* __restrict__ partials_out) {
    __shared__ unsigned short aT[32 * 584];   // 37,376 B: 32 px rows, pitch 584 halves
    __shared__ unsigned       coordA[576];    //  2,304 B: y0 | xc<<8 | fy16<<16

    int t = threadIdx.x;
    int L = t & 63, nt = t >> 6;
    int b, h, wt;
    swizzle_bhw(blockIdx.x, b, h, wt);
    int w0 = wt << 6;

    // Phase A: 64 threads, one pixel each: GN+tanh -> outward cumsum -> coords
    if (t < 64) {
        int w = w0 + t;
        float tk[9];
#pragma unroll
        for (int k = 0; k < 9; ++k) {
            unsigned short u = off_raw[((b * NOFF + k) << 16) + (h << 8) + w];
            float vv = __half2float(*(__half*)&u);
            int g = k >> 1;
            float mean = stats_off[(b * 5 + g) * 2];
            float rstd = stats_off[(b * 5 + g) * 2 + 1];
            tk[k] = tanhf((vv - mean) * rstd * gno_w[k] + gno_b[k]);
        }
        float yc[9];
        float c = 0.f;
#pragma unroll
        for (int k = 3; k >= 0; --k) { c += tk[k]; yc[k] = c; }
        yc[4] = 0.f;
        c = 0.f;
#pragma unroll
        for (int k = 5; k < 9; ++k) { c += tk[k]; yc[k] = c; }
#pragma unroll
        for (int k = 0; k < 9; ++k) {
            float y = fminf(fmaxf((float)h + yc[k], 0.f), 255.f);
            float y0f = floorf(y);
            int y0 = (int)y0f;
            int xc = min(max(w + k - 4, 0), 255);
            __half fh = __float2half(y - y0f);
            coordA[t * 9 + k] = (unsigned)y0 | ((unsigned)xc << 8)
                              | ((unsigned)(*(unsigned short*)&fh) << 16);
        }
    }

    s16x8 wreg[18];
#pragma unroll
    for (int kb = 0; kb < 18; ++kb)
        wreg[kb] = *(const s16x8*)(wdscB + ((nt * 18 + kb) * 64 + L) * 8);

    int col = L & 15, quad = L >> 4;
    int co = nt * 16 + col;
    float bias = b_dsc[co];
    float ss = 0.f, ss2 = 0.f;
    int bBase = b << 22;                  // b * 256*256*64

    for (int round = 0; round < 2; ++round) {
        __syncthreads();   // coordA ready (round 0) / aT free (round 1)
        // stage 32 px: 32*9*8 = 2304 chunk-items, 9 iters
#pragma unroll
        for (int it = 0; it < 9; ++it) {
            int idx = it * 256 + t;
            int cg  = idx & 7;
            int r2  = idx >> 3;            // 0..287
            int pxl = r2 / 9;
            int k   = r2 - pxl * 9;
            int pi  = (round * 32 + pxl) * 9 + k;
            unsigned pc = coordA[pi];
            int o0 = bBase + ((pc & 255) << 14) + (((pc >> 8) & 255) << 6) + cg * 8;
            unsigned short fb = (unsigned short)(pc >> 16);
            int o1 = fb ? o0 + 16384 : o0;      // +1 row (256*64) iff fy != 0
            __half fh = *(__half*)&fb;
            __half2 fy2 = __half2half2(fh);
            uint4 u0 = *(const uint4*)(xTh + o0);
            uint4 u1 = *(const uint4*)(xTh + o1);
            uint4 d;
            d.x = lerp2h(u0.x, u1.x, fy2);
            d.y = lerp2h(u0.y, u1.y, fy2);
            d.z = lerp2h(u0.z, u1.z, fy2);
            d.w = lerp2h(u0.w, u1.w, fy2);
            int c2 = (cg + k) & 7;
            *(uint4*)&aT[pxl * 584 + k * 64 + c2 * 8] = d;
        }
        __syncthreads();

#pragma unroll
        for (int sub = 0; sub < 2; ++sub) {
            int row = sub * 16 + col;      // A row = pixel
            f32x4 acc = {0.f, 0.f, 0.f, 0.f};
#pragma unroll
            for (int kb = 0; kb < 18; ++kb) {
                int k  = kb >> 1;
                int cch = ((kb & 1) << 2) + quad;
                int c2 = (cch + k) & 7;
                s16x8 a = *(const s16x8*)&aT[row * 584 + k * 64 + c2 * 8];
                acc = __builtin_amdgcn_mfma_f32_16x16x32_f16(a, wreg[kb], acc, 0, 0, 0);
            }
            int wbase = w0 + round * 32 + sub * 16 + quad * 4;
            size_t obase = ((size_t)((b << 16) + (h << 8) + wbase)) * 64 + co;
#pragma unroll
            for (int r = 0; r < 4; ++r) {
                float val = acc[r] + bias;
                ss += val; ss2 += val * val;
                __half hv = __float2half(val);
                tmph[obase + (size_t)r * 64] = *(unsigned short*)&hv;
            }
        }
    }
    // per-block GN partials: sum over 64 px (quads) then over the 4 channels of each group
    ss  += __shfl_xor(ss, 16, 64);  ss  += __shfl_xor(ss, 32, 64);
    ss2 += __shfl_xor(ss2, 16, 64); ss2 += __shfl_xor(ss2, 32, 64);
    float sg = ss, sg2 = ss2;
    sg  += __shfl_xor(sg, 1, 64);  sg  += __shfl_xor(sg, 2, 64);
    sg2 += __shfl_xor(sg2, 1, 64); sg2 += __shfl_xor(sg2, 2, 64);
    if (quad == 0 && (col & 3) == 0) {
        int gi = nt * 4 + (col >> 2);      // 0..15
        partials_out[(size_t)blockIdx.x * 32 + gi * 2]     = sg;
        partials_out[(size_t)blockIdx.x * 32 + gi * 2 + 1] = sg2;
    }
}

// ---------------- final: NHWC fp16 tmp -> GN -> ReLU -> NCHW fp32 out ----------------
__global__ __launch_bounds__(256) void apply_final_kernel(const unsigned short* __restrict__ tmph,
                                                          const float* __restrict__ stats_out,
                                                          const float* __restrict__ gn_w,
                                                          const float* __restrict__ gn_b,
                                                          float* __restrict__ out) {
    __shared__ float tile[64 * 65];
    int wt = blockIdx.x & 3;
    int h  = (blockIdx.x >> 2) & 255;
    int b  = blockIdx.x >> 10;
    int w0 = wt * 64;
    int t  = threadIdx.x;
    {
        int c2 = t & 31, wrow = t >> 5;
        int co0 = c2 * 2;
        int g = co0 >> 2;
        float mean = stats_out[(b * 16 + g) * 2];
        float rstd = stats_out[(b * 16 + g) * 2 + 1];
        float sc0 = rstd * gn_w[co0],     sh0 = gn_b[co0]     - mean * sc0;
        float sc1 = rstd * gn_w[co0 + 1], sh1 = gn_b[co0 + 1] - mean * sc1;
        const unsigned* src = (const unsigned*)tmph;
        for (int it = 0; it < 8; ++it) {
            int wl = wrow + it * 8;
            unsigned u = src[(((b * HH + h) * WW) + w0 + wl) * 32 + c2];  // coalesced over c
            float2 f = __half22float2(*(__half2*)&u);
            tile[co0 * 65 + wl]       = fmaxf(fmaf(f.x, sc0, sh0), 0.f);
            tile[(co0 + 1) * 65 + wl] = fmaxf(fmaf(f.y, sc1, sh1), 0.f);
        }
    }
    __syncthreads();
    {
        int wl = t & 63, crow = t >> 6;
        for (int it = 0; it < 16; ++it) {
            int co = crow + it * 4;
            out[((size_t)(b * CC + co) * HH + h) * WW + w0 + wl] = tile[co * 65 + wl];
        }
    }
}

extern "C" void kernel_launch(void* const* d_in, const int* in_sizes, int n_in,
                              void* d_out, int out_size, void* d_ws, size_t ws_size,
                              hipStream_t stream) {
    const float* x     = (const float*)d_in[0];
    const float* w_off = (const float*)d_in[1];
    const float* b_off = (const float*)d_in[2];
    const float* gno_w = (const float*)d_in[3];
    const float* gno_b = (const float*)d_in[4];
    const float* w_dsc = (const float*)d_in[5];
    const float* b_dsc = (const float*)d_in[6];
    const float* gn_w  = (const float*)d_in[7];
    const float* gn_b  = (const float*)d_in[8];
    float* out = (float*)d_out;

    char* ws = (char*)d_ws;
    unsigned short* xTh     = (unsigned short*)(ws);               // 16,777,216 B
    unsigned short* tmph    = (unsigned short*)(ws + 16777216);    // 16,777,216 B
    unsigned short* off_raw = (unsigned short*)(ws + 33554432);    //  2,621,440 B (fp16)
    unsigned short* wdscB   = (unsigned short*)(ws + 36175872);    //     73,728 B
    unsigned short* woffB   = (unsigned short*)(ws + 36249600);    //     18,432 B
    float* stats_off        = (float*)(ws + 36268032);             //        256 B
    float* stats_out        = (float*)(ws + 36268288);             //        256 B
    float* partials_off     = (float*)(ws + 36268544);             //    163,840 B
    float* partials_out     = (float*)(ws + 36432384);             //    262,144 B

    hipLaunchKernelGGL(transpose_x_kernel, dim3(2192), dim3(256), 0, stream,
                       x, xTh, w_off, w_dsc, woffB, wdscB);
    hipLaunchKernelGGL(conv_off_mfma, dim3(2048), dim3(256), 0, stream,
                       xTh, woffB, b_off, off_raw, partials_off);
    hipLaunchKernelGGL(reduce_off_kernel, dim3(10), dim3(256), 0, stream,
                       partials_off, stats_off);
    hipLaunchKernelGGL(main_mfma, dim3(2048), dim3(256), 0, stream,
                       xTh, off_raw, stats_off, gno_w, gno_b, wdscB, b_dsc,
                       tmph, partials_out);
    hipLaunchKernelGGL(reduce_out_kernel, dim3(32), dim3(256), 0, stream,
                       partials_out, stats_out);
    hipLaunchKernelGGL(apply_final_kernel, dim3(2048), dim3(256), 0, stream,
                       tmph, stats_out, gn_w, gn_b, out);
}